// Round 4
// baseline (439.313 us; speedup 1.0000x reference)
//
#include <hip/hip_runtime.h>
#include <math.h>

#define CDIV(a, b) (((a) + (b) - 1) / (b))

// ---------- 3x3 stride-2 pad-1 conv + bias + relu ----------
__global__ void conv3x3_s2_relu(const float* __restrict__ in, const float* __restrict__ w,
                                const float* __restrict__ bias, float* __restrict__ out,
                                int B, int Cin, int Hin, int Cout, int Hout) {
    int t = blockIdx.x * blockDim.x + threadIdx.x;
    int total = B * Cout * Hout * Hout;
    if (t >= total) return;
    int wo = t % Hout;
    int ho = (t / Hout) % Hout;
    int co = (t / (Hout * Hout)) % Cout;
    int b  = t / (Hout * Hout * Cout);
    float acc = bias[co];
    for (int ci = 0; ci < Cin; ++ci) {
        const float* ip = in + (size_t)(b * Cin + ci) * Hin * Hin;
        const float* wp = w + (size_t)(co * Cin + ci) * 9;
        #pragma unroll
        for (int kh = 0; kh < 3; ++kh) {
            int hi = 2 * ho + kh - 1;
            if (hi < 0 || hi >= Hin) continue;
            #pragma unroll
            for (int kw = 0; kw < 3; ++kw) {
                int wi = 2 * wo + kw - 1;
                if (wi < 0 || wi >= Hin) continue;
                acc += wp[kh * 3 + kw] * ip[hi * Hin + wi];
            }
        }
    }
    out[t] = fmaxf(acc, 0.f);
}

// ---------- fused qkv projection: tile in LDS, coalesced padded stores ----------
// grid = B * (N/64); block 256. q/k/v layout: [bh][n][DP] (DP = padded d, 16B-aligned rows)
template <int C, int INNER, int DP, int DD, bool ZS>
__global__ void qkv_fused(const float* __restrict__ z, const float* __restrict__ w,
                          const float* __restrict__ bias, float* __restrict__ q,
                          float* __restrict__ k, float* __restrict__ v, int N) {
    constexpr int OC3 = 3 * INNER;
    __shared__ float tile[OC3 * 65];
    __shared__ float zs[ZS ? C * 64 : 1];
    const int ntiles = N >> 6;
    const int bb = blockIdx.x / ntiles;
    const int n0 = (blockIdx.x % ntiles) << 6;
    const int tid = threadIdx.x;

    if (ZS) {
        for (int t = tid; t < C * 64; t += 256) {
            int c = t >> 6, n = t & 63;
            zs[t] = z[(size_t)(bb * C + c) * N + n0 + n];
        }
        __syncthreads();
    }
    for (int t = tid; t < OC3 * 64; t += 256) {
        int oc = t >> 6, n = t & 63;
        float val = bias[oc];
        const float* wp = w + (size_t)oc * C;
        if (ZS) {
            #pragma unroll 8
            for (int c = 0; c < C; ++c) val = fmaf(wp[c], zs[c * 64 + n], val);
        } else {
            const float* zp = z + (size_t)(bb * C) * N + n0 + n;
            #pragma unroll 8
            for (int c = 0; c < C; ++c) val = fmaf(wp[c], zp[(size_t)c * N], val);
        }
        tile[oc * 65 + n] = val;
    }
    __syncthreads();
    constexpr int RSZ = 64 * DP;
    for (int t = tid; t < 9 * RSZ; t += 256) {
        int region = t / RSZ;
        int r = t - region * RSZ;
        int p = region / 3, hh = region - p * 3;
        int n = r / DP, s = r - n * DP;
        float val = (s < DD) ? tile[(p * INNER + s * 3 + hh) * 65 + n] : 0.f;
        float* dst = (p == 0) ? q : (p == 1) ? k : v;
        dst[((size_t)(bb * 3 + hh) * N + n0 + n) * DP + s] = val;
    }
}

// ---------- attention: no-max softmax, K/V uniform global loads w/ register dbuf ----------
// grid = 96 * IC (bh = blockIdx%96 -> same-bh blocks share XCD L2). block = 256 = 4 waves.
// wave w takes j in [w*N/4,(w+1)*N/4); thread owns RPT rows; combine via LDS (odd stride).
template <int D, int DP, int RPT>
__global__ void attn3(const float* __restrict__ q, const float* __restrict__ k,
                      const float* __restrict__ v, const float* __restrict__ table,
                      float* __restrict__ o, int N, int log2Hg, int T, float scale) {
    extern __shared__ float smem[];
    float* tb = smem;    // T floats, pre-scaled by `scale`
    float* comb = smem;  // overlays tb after the j-loop
    constexpr int ROWS = 64 * RPT;
    constexpr int CSTR = (D % 2 == 0) ? (D + 3) : (D + 2);  // odd -> conflict-free
    constexpr int NV4 = DP / 4;

    const int bh = blockIdx.x % 96;
    const int chunk = blockIdx.x / 96;
    const int h = bh % 3;
    const int tid = threadIdx.x;
    const int wave = tid >> 6;
    const int lane = tid & 63;
    const int Hg = 1 << log2Hg;
    const int W2 = 2 * Hg - 1;
    const int base = chunk * ROWS;

    for (int t = tid; t < T; t += 256) tb[t] = table[t * 3 + h] * scale;

    float qr[RPT][D];
    int ibase[RPT];
    #pragma unroll
    for (int r = 0; r < RPT; ++r) {
        int i = base + lane + 64 * r;
        const float* qg = q + ((size_t)bh * N + i) * DP;
        #pragma unroll
        for (int dd = 0; dd < D; ++dd) qr[r][dd] = qg[dd];
        ibase[r] = ((i >> log2Hg) + Hg - 1) * W2 + (i & (Hg - 1)) + Hg - 1;
    }
    __syncthreads();

    float acc[RPT][D];
    float lsum[RPT];
    #pragma unroll
    for (int r = 0; r < RPT; ++r) {
        lsum[r] = 0.f;
        #pragma unroll
        for (int dd = 0; dd < D; ++dd) acc[r][dd] = 0.f;
    }

    const float4* kb = (const float4*)(k + (size_t)bh * N * DP);
    const float4* vb = (const float4*)(v + (size_t)bh * N * DP);
    const int NJ = N >> 2;
    const int j0 = wave * NJ;

    float4 k0[NV4], v0[NV4], k1[NV4], v1[NV4];
    #pragma unroll
    for (int x = 0; x < NV4; ++x) { k0[x] = kb[(size_t)j0 * NV4 + x]; v0[x] = vb[(size_t)j0 * NV4 + x]; }

    auto compute = [&](int j, const float4* kr4, const float4* vr4) {
        const float* kr = (const float*)kr4;
        const float* vr = (const float*)vr4;
        int joff = (j >> log2Hg) * W2 + (j & (Hg - 1));
        #pragma unroll
        for (int r = 0; r < RPT; ++r) {
            float s = 0.f;
            #pragma unroll
            for (int dd = 0; dd < D; ++dd) s = fmaf(qr[r][dd], kr[dd], s);
            float e = __expf(fmaf(s, scale, tb[ibase[r] - joff]));
            lsum[r] += e;
            #pragma unroll
            for (int dd = 0; dd < D; ++dd) acc[r][dd] = fmaf(e, vr[dd], acc[r][dd]);
        }
    };

    for (int jj = 0; jj < NJ; jj += 2) {
        int j = j0 + jj;
        #pragma unroll
        for (int x = 0; x < NV4; ++x) { k1[x] = kb[(size_t)(j + 1) * NV4 + x]; v1[x] = vb[(size_t)(j + 1) * NV4 + x]; }
        compute(j, k0, v0);
        // benign over-read of one row past the wave's range (lands in the next ws buffer)
        #pragma unroll
        for (int x = 0; x < NV4; ++x) { k0[x] = kb[(size_t)(j + 2) * NV4 + x]; v0[x] = vb[(size_t)(j + 2) * NV4 + x]; }
        compute(j + 1, k1, v1);
    }

    __syncthreads();
    #pragma unroll
    for (int r = 0; r < RPT; ++r) {
        float* cp = comb + (size_t)(wave * ROWS + lane + 64 * r) * CSTR;
        #pragma unroll
        for (int dd = 0; dd < D; ++dd) cp[dd] = acc[r][dd];
        cp[D] = lsum[r];
    }
    __syncthreads();
    if (tid < ROWS) {
        float af[D];
        #pragma unroll
        for (int dd = 0; dd < D; ++dd) af[dd] = 0.f;
        float lf = 0.f;
        #pragma unroll
        for (int wv = 0; wv < 4; ++wv) {
            const float* cp = comb + (size_t)(wv * ROWS + tid) * CSTR;
            #pragma unroll
            for (int dd = 0; dd < D; ++dd) af[dd] += cp[dd];
            lf += cp[D];
        }
        float inv = 1.0f / lf;
        int i = base + tid;
        #pragma unroll
        for (int dd = 0; dd < D; ++dd)
            o[((size_t)bh * D + dd) * N + i] = af[dd] * inv;  // O layout [bh][d][N]
    }
}

// ---------- output projection + bias + residual; o layout [bh][d][N] ----------
__global__ void outproj_residual(const float* __restrict__ o, const float* __restrict__ w,
                                 const float* __restrict__ bias, const float* __restrict__ zin,
                                 float* __restrict__ zout, int B, int dim, int inner, int N,
                                 int heads, int d) {
    int t = blockIdx.x * blockDim.x + threadIdx.x;
    int total = B * dim * N;
    if (t >= total) return;
    int n = t % N;
    int c = (t / N) % dim;
    int b = t / (N * dim);
    float val = bias[c] + zin[t];
    const float* wp = w + (size_t)c * inner;
    for (int dd = 0; dd < d; ++dd) {
        #pragma unroll
        for (int hh = 0; hh < 3; ++hh) {
            val += wp[dd * 3 + hh] * o[((size_t)((b * 3 + hh) * d) + dd) * N + n];
        }
    }
    zout[t] = val;
}

// ---------- fused global avg pool + classifier ----------
__global__ void pool_cls(const float* __restrict__ z, const float* __restrict__ w,
                         const float* __restrict__ bias, float* __restrict__ out) {
    __shared__ float p[64];
    int b = blockIdx.x;
    int c = threadIdx.x;  // 64 threads
    const float* zp = z + ((size_t)b * 64 + c) * 64;
    float s = 0.f;
    #pragma unroll
    for (int n = 0; n < 64; ++n) s += zp[n];
    s *= (1.0f / 64.0f);
    p[c] = s;
    out[b * 64 + c] = s;
    __syncthreads();
    if (c < 10) {
        float val = bias[c];
        const float* wp = w + (size_t)c * 64;
        #pragma unroll
        for (int kk = 0; kk < 64; ++kk) val += wp[kk] * p[kk];
        out[2048 + b * 10 + c] = val;
    }
}

extern "C" void kernel_launch(void* const* d_in, const int* in_sizes, int n_in,
                              void* d_out, int out_size, void* d_ws, size_t ws_size,
                              hipStream_t stream) {
    const int B = 32, HEADS = 3, BS = 256;
    const float* x = (const float*)d_in[0];
    float* out = (float*)d_out;

    float* ws = (float*)d_ws;
    float* Z0 = ws;               // 524288
    float* Z1 = Z0 + 524288;      // 524288
    float* Q  = Z1 + 524288;      // 786432 (96*1024*8 max)
    float* K  = Q + 786432;
    float* V  = K + 786432;
    float* O  = V + 786432;       // 491520 (96*1024*5 max)

    // ===== layer 1: Cin=1 H64->32, dim=16, inner=15, d=5 (pad 8), N=1024, Hg=32 =====
    {
        const int Cin = 1, dim = 16, Hin = 64, Hout = 32, N = 1024;
        conv3x3_s2_relu<<<CDIV(B * dim * Hout * Hout, BS), BS, 0, stream>>>(
            x, (const float*)d_in[1], (const float*)d_in[2], Z0, B, Cin, Hin, dim, Hout);
        qkv_fused<16, 15, 8, 5, true><<<B * (N / 64), 256, 0, stream>>>(
            Z0, (const float*)d_in[3], (const float*)d_in[4], Q, K, V, N);
        // IC=8, ROWS=128: grid 768 = 3 blocks/CU balanced. LDS = max(T, 4*128*7)*4 = 15876B
        attn3<5, 8, 2><<<96 * 8, 256, 3969 * 4, stream>>>(
            Q, K, V, (const float*)d_in[7], O, N, 5, 3969, 1.0f / sqrtf(5.0f));
        outproj_residual<<<CDIV(B * dim * N, BS), BS, 0, stream>>>(
            O, (const float*)d_in[5], (const float*)d_in[6], Z0, Z1, B, dim, 15, N, HEADS, 5);
    }
    // ===== layer 2: Cin=16 H32->16, dim=32, inner=30, d=10 (pad 12), N=256, Hg=16 =====
    {
        const int Cin = 16, dim = 32, Hin = 32, Hout = 16, N = 256;
        conv3x3_s2_relu<<<CDIV(B * dim * Hout * Hout, BS), BS, 0, stream>>>(
            Z1, (const float*)d_in[8], (const float*)d_in[9], Z0, B, Cin, Hin, dim, Hout);
        qkv_fused<32, 30, 12, 10, true><<<B * (N / 64), 256, 0, stream>>>(
            Z0, (const float*)d_in[10], (const float*)d_in[11], Q, K, V, N);
        // IC=4, ROWS=64: grid 384. LDS = 4*64*13*4 = 13312B
        attn3<10, 12, 1><<<96 * 4, 256, 13312, stream>>>(
            Q, K, V, (const float*)d_in[14], O, N, 4, 961, 1.0f / sqrtf(10.0f));
        outproj_residual<<<CDIV(B * dim * N, BS), BS, 0, stream>>>(
            O, (const float*)d_in[12], (const float*)d_in[13], Z0, Z1, B, dim, 30, N, HEADS, 10);
    }
    // ===== layer 3: Cin=32 H16->8, dim=64, inner=63, d=21 (pad 24), N=64, Hg=8 =====
    {
        const int Cin = 32, dim = 64, Hin = 16, Hout = 8, N = 64;
        conv3x3_s2_relu<<<CDIV(B * dim * Hout * Hout, BS), BS, 0, stream>>>(
            Z1, (const float*)d_in[15], (const float*)d_in[16], Z0, B, Cin, Hin, dim, Hout);
        qkv_fused<64, 63, 24, 21, false><<<B * (N / 64), 256, 0, stream>>>(
            Z0, (const float*)d_in[17], (const float*)d_in[18], Q, K, V, N);
        // IC=1, ROWS=64: grid 96. LDS = 4*64*23*4 = 23552B
        attn3<21, 24, 1><<<96, 256, 23552, stream>>>(
            Q, K, V, (const float*)d_in[21], O, N, 3, 225, 1.0f / sqrtf(21.0f));
        outproj_residual<<<CDIV(B * dim * N, BS), BS, 0, stream>>>(
            O, (const float*)d_in[19], (const float*)d_in[20], Z0, Z1, B, dim, 63, N, HEADS, 21);
    }
    // ---- fused pool + cls ----
    pool_cls<<<B, 64, 0, stream>>>(Z1, (const float*)d_in[22], (const float*)d_in[23], out);
}

// Round 5
// 364.649 us; speedup vs baseline: 1.2048x; 1.2048x over previous
//
#include <hip/hip_runtime.h>
#include <math.h>

#define CDIV(a, b) (((a) + (b) - 1) / (b))

// ---------- 3x3 stride-2 pad-1 conv + bias + relu ----------
__global__ void conv3x3_s2_relu(const float* __restrict__ in, const float* __restrict__ w,
                                const float* __restrict__ bias, float* __restrict__ out,
                                int B, int Cin, int Hin, int Cout, int Hout) {
    int t = blockIdx.x * blockDim.x + threadIdx.x;
    int total = B * Cout * Hout * Hout;
    if (t >= total) return;
    int wo = t % Hout;
    int ho = (t / Hout) % Hout;
    int co = (t / (Hout * Hout)) % Cout;
    int b  = t / (Hout * Hout * Cout);
    float acc = bias[co];
    for (int ci = 0; ci < Cin; ++ci) {
        const float* ip = in + (size_t)(b * Cin + ci) * Hin * Hin;
        const float* wp = w + (size_t)(co * Cin + ci) * 9;
        #pragma unroll
        for (int kh = 0; kh < 3; ++kh) {
            int hi = 2 * ho + kh - 1;
            if (hi < 0 || hi >= Hin) continue;
            #pragma unroll
            for (int kw = 0; kw < 3; ++kw) {
                int wi = 2 * wo + kw - 1;
                if (wi < 0 || wi >= Hin) continue;
                acc += wp[kh * 3 + kw] * ip[hi * Hin + wi];
            }
        }
    }
    out[t] = fmaxf(acc, 0.f);
}

// ---------- qkv projection, elementwise (max parallelism); writes padded [bh][n][DP] ----------
__global__ void qkv_proj(const float* __restrict__ z, const float* __restrict__ w,
                         const float* __restrict__ bias, float* __restrict__ q,
                         float* __restrict__ k, float* __restrict__ v,
                         int B, int C, int N, int inner, int DP) {
    int t = blockIdx.x * blockDim.x + threadIdx.x;
    int total = B * N * 3 * inner;
    if (t >= total) return;
    int n  = t % N;
    int oc = (t / N) % (3 * inner);
    int b  = t / (N * 3 * inner);
    float val = bias[oc];
    const float* zp = z + (size_t)b * C * N + n;
    const float* wp = w + (size_t)oc * C;
    #pragma unroll 8
    for (int c = 0; c < C; ++c) val = fmaf(wp[c], zp[(size_t)c * N], val);
    int part = oc / inner;
    int r = oc - part * inner;
    int hh = r % 3;   // heads fastest in channel layout
    int dd = r / 3;
    float* dst = part == 0 ? q : (part == 1 ? k : v);
    dst[((size_t)(b * 3 + hh) * N + n) * DP + dd] = val;
}

// ---------- attention: no-max softmax, K/V uniform global loads w/ register dbuf ----------
// grid = 96 * IC (bh = blockIdx%96 -> same-bh blocks share XCD L2). block = 256 = 4 waves.
// wave w takes j in [w*N/4,(w+1)*N/4); thread owns RPT rows; combine via LDS (odd stride).
template <int D, int DP, int RPT>
__global__ void attn3(const float* __restrict__ q, const float* __restrict__ k,
                      const float* __restrict__ v, const float* __restrict__ table,
                      float* __restrict__ o, int N, int log2Hg, int T, float scale) {
    extern __shared__ float smem[];
    float* tb = smem;    // T floats, pre-scaled by `scale`
    float* comb = smem;  // overlays tb after the j-loop
    constexpr int ROWS = 64 * RPT;
    constexpr int CSTR = (D % 2 == 0) ? (D + 3) : (D + 2);  // odd -> conflict-free
    constexpr int NV4 = DP / 4;

    const int bh = blockIdx.x % 96;
    const int chunk = blockIdx.x / 96;
    const int h = bh % 3;
    const int tid = threadIdx.x;
    const int wave = tid >> 6;
    const int lane = tid & 63;
    const int Hg = 1 << log2Hg;
    const int W2 = 2 * Hg - 1;
    const int base = chunk * ROWS;

    for (int t = tid; t < T; t += 256) tb[t] = table[t * 3 + h] * scale;

    float qr[RPT][D];
    int ibase[RPT];
    #pragma unroll
    for (int r = 0; r < RPT; ++r) {
        int i = base + lane + 64 * r;
        const float* qg = q + ((size_t)bh * N + i) * DP;
        #pragma unroll
        for (int dd = 0; dd < D; ++dd) qr[r][dd] = qg[dd];
        ibase[r] = ((i >> log2Hg) + Hg - 1) * W2 + (i & (Hg - 1)) + Hg - 1;
    }
    __syncthreads();

    float acc[RPT][D];
    float lsum[RPT];
    #pragma unroll
    for (int r = 0; r < RPT; ++r) {
        lsum[r] = 0.f;
        #pragma unroll
        for (int dd = 0; dd < D; ++dd) acc[r][dd] = 0.f;
    }

    const float4* kb = (const float4*)(k + (size_t)bh * N * DP);
    const float4* vb = (const float4*)(v + (size_t)bh * N * DP);
    const int NJ = N >> 2;
    const int j0 = wave * NJ;

    float4 k0[NV4], v0[NV4], k1[NV4], v1[NV4];
    #pragma unroll
    for (int x = 0; x < NV4; ++x) { k0[x] = kb[(size_t)j0 * NV4 + x]; v0[x] = vb[(size_t)j0 * NV4 + x]; }

    auto compute = [&](int j, const float4* kr4, const float4* vr4) {
        const float* kr = (const float*)kr4;
        const float* vr = (const float*)vr4;
        int joff = (j >> log2Hg) * W2 + (j & (Hg - 1));
        #pragma unroll
        for (int r = 0; r < RPT; ++r) {
            float s = 0.f;
            #pragma unroll
            for (int dd = 0; dd < D; ++dd) s = fmaf(qr[r][dd], kr[dd], s);
            float e = __expf(fmaf(s, scale, tb[ibase[r] - joff]));
            lsum[r] += e;
            #pragma unroll
            for (int dd = 0; dd < D; ++dd) acc[r][dd] = fmaf(e, vr[dd], acc[r][dd]);
        }
    };

    for (int jj = 0; jj < NJ; jj += 2) {
        int j = j0 + jj;
        #pragma unroll
        for (int x = 0; x < NV4; ++x) { k1[x] = kb[(size_t)(j + 1) * NV4 + x]; v1[x] = vb[(size_t)(j + 1) * NV4 + x]; }
        compute(j, k0, v0);
        // benign over-read of one row past the wave's range (lands in the next ws buffer)
        #pragma unroll
        for (int x = 0; x < NV4; ++x) { k0[x] = kb[(size_t)(j + 2) * NV4 + x]; v0[x] = vb[(size_t)(j + 2) * NV4 + x]; }
        compute(j + 1, k1, v1);
    }

    __syncthreads();
    #pragma unroll
    for (int r = 0; r < RPT; ++r) {
        float* cp = comb + (size_t)(wave * ROWS + lane + 64 * r) * CSTR;
        #pragma unroll
        for (int dd = 0; dd < D; ++dd) cp[dd] = acc[r][dd];
        cp[D] = lsum[r];
    }
    __syncthreads();
    if (tid < ROWS) {
        float af[D];
        #pragma unroll
        for (int dd = 0; dd < D; ++dd) af[dd] = 0.f;
        float lf = 0.f;
        #pragma unroll
        for (int wv = 0; wv < 4; ++wv) {
            const float* cp = comb + (size_t)(wv * ROWS + tid) * CSTR;
            #pragma unroll
            for (int dd = 0; dd < D; ++dd) af[dd] += cp[dd];
            lf += cp[D];
        }
        float inv = 1.0f / lf;
        int i = base + tid;
        #pragma unroll
        for (int dd = 0; dd < D; ++dd)
            o[((size_t)bh * D + dd) * N + i] = af[dd] * inv;  // O layout [bh][d][N]
    }
}

// ---------- output projection + bias + residual; o layout [bh][d][N] ----------
__global__ void outproj_residual(const float* __restrict__ o, const float* __restrict__ w,
                                 const float* __restrict__ bias, const float* __restrict__ zin,
                                 float* __restrict__ zout, int B, int dim, int inner, int N,
                                 int heads, int d) {
    int t = blockIdx.x * blockDim.x + threadIdx.x;
    int total = B * dim * N;
    if (t >= total) return;
    int n = t % N;
    int c = (t / N) % dim;
    int b = t / (N * dim);
    float val = bias[c] + zin[t];
    const float* wp = w + (size_t)c * inner;
    for (int dd = 0; dd < d; ++dd) {
        #pragma unroll
        for (int hh = 0; hh < 3; ++hh) {
            val += wp[dd * 3 + hh] * o[((size_t)((b * 3 + hh) * d) + dd) * N + n];
        }
    }
    zout[t] = val;
}

// ---------- fused global avg pool + classifier ----------
__global__ void pool_cls(const float* __restrict__ z, const float* __restrict__ w,
                         const float* __restrict__ bias, float* __restrict__ out) {
    __shared__ float p[64];
    int b = blockIdx.x;
    int c = threadIdx.x;  // 64 threads
    const float* zp = z + ((size_t)b * 64 + c) * 64;
    float s = 0.f;
    #pragma unroll
    for (int n = 0; n < 64; ++n) s += zp[n];
    s *= (1.0f / 64.0f);
    p[c] = s;
    out[b * 64 + c] = s;
    __syncthreads();
    if (c < 10) {
        float val = bias[c];
        const float* wp = w + (size_t)c * 64;
        #pragma unroll
        for (int kk = 0; kk < 64; ++kk) val += wp[kk] * p[kk];
        out[2048 + b * 10 + c] = val;
    }
}

extern "C" void kernel_launch(void* const* d_in, const int* in_sizes, int n_in,
                              void* d_out, int out_size, void* d_ws, size_t ws_size,
                              hipStream_t stream) {
    const int B = 32, HEADS = 3, BS = 256;
    const float* x = (const float*)d_in[0];
    float* out = (float*)d_out;

    float* ws = (float*)d_ws;
    float* Z0 = ws;               // 524288
    float* Z1 = Z0 + 524288;      // 524288
    float* Q  = Z1 + 524288;      // 786432 (96*1024*8 max)
    float* K  = Q + 786432;
    float* V  = K + 786432;
    float* O  = V + 786432;       // 491520 (96*1024*5 max)

    // ===== layer 1: Cin=1 H64->32, dim=16, inner=15, d=5 (pad 8), N=1024, Hg=32 =====
    {
        const int Cin = 1, dim = 16, Hin = 64, Hout = 32, N = 1024, inner = 15, DP = 8;
        conv3x3_s2_relu<<<CDIV(B * dim * Hout * Hout, BS), BS, 0, stream>>>(
            x, (const float*)d_in[1], (const float*)d_in[2], Z0, B, Cin, Hin, dim, Hout);
        qkv_proj<<<CDIV(B * N * 3 * inner, BS), BS, 0, stream>>>(
            Z0, (const float*)d_in[3], (const float*)d_in[4], Q, K, V, B, dim, N, inner, DP);
        // IC=8, ROWS=128: grid 768 = 3 blocks/CU balanced. LDS = max(T, 4*128*7)*4 = 15876B
        attn3<5, 8, 2><<<96 * 8, 256, 3969 * 4, stream>>>(
            Q, K, V, (const float*)d_in[7], O, N, 5, 3969, 1.0f / sqrtf(5.0f));
        outproj_residual<<<CDIV(B * dim * N, BS), BS, 0, stream>>>(
            O, (const float*)d_in[5], (const float*)d_in[6], Z0, Z1, B, dim, inner, N, HEADS, 5);
    }
    // ===== layer 2: Cin=16 H32->16, dim=32, inner=30, d=10 (pad 12), N=256, Hg=16 =====
    {
        const int Cin = 16, dim = 32, Hin = 32, Hout = 16, N = 256, inner = 30, DP = 12;
        conv3x3_s2_relu<<<CDIV(B * dim * Hout * Hout, BS), BS, 0, stream>>>(
            Z1, (const float*)d_in[8], (const float*)d_in[9], Z0, B, Cin, Hin, dim, Hout);
        qkv_proj<<<CDIV(B * N * 3 * inner, BS), BS, 0, stream>>>(
            Z0, (const float*)d_in[10], (const float*)d_in[11], Q, K, V, B, dim, N, inner, DP);
        // IC=4, ROWS=64: grid 384. LDS = 4*64*13*4 = 13312B
        attn3<10, 12, 1><<<96 * 4, 256, 13312, stream>>>(
            Q, K, V, (const float*)d_in[14], O, N, 4, 961, 1.0f / sqrtf(10.0f));
        outproj_residual<<<CDIV(B * dim * N, BS), BS, 0, stream>>>(
            O, (const float*)d_in[12], (const float*)d_in[13], Z0, Z1, B, dim, inner, N, HEADS, 10);
    }
    // ===== layer 3: Cin=32 H16->8, dim=64, inner=63, d=21 (pad 24), N=64, Hg=8 =====
    {
        const int Cin = 32, dim = 64, Hin = 16, Hout = 8, N = 64, inner = 63, DP = 24;
        conv3x3_s2_relu<<<CDIV(B * dim * Hout * Hout, BS), BS, 0, stream>>>(
            Z1, (const float*)d_in[15], (const float*)d_in[16], Z0, B, Cin, Hin, dim, Hout);
        qkv_proj<<<CDIV(B * N * 3 * inner, BS), BS, 0, stream>>>(
            Z0, (const float*)d_in[17], (const float*)d_in[18], Q, K, V, B, dim, N, inner, DP);
        // IC=1, ROWS=64: grid 96. LDS = 4*64*23*4 = 23552B
        attn3<21, 24, 1><<<96, 256, 23552, stream>>>(
            Q, K, V, (const float*)d_in[21], O, N, 3, 225, 1.0f / sqrtf(21.0f));
        outproj_residual<<<CDIV(B * dim * N, BS), BS, 0, stream>>>(
            O, (const float*)d_in[19], (const float*)d_in[20], Z0, Z1, B, dim, inner, N, HEADS, 21);
    }
    // ---- fused pool + cls ----
    pool_cls<<<B, 64, 0, stream>>>(Z1, (const float*)d_in[22], (const float*)d_in[23], out);
}